// Round 7
// baseline (138.626 us; speedup 1.0000x reference)
//
#include <hip/hip_runtime.h>

// CondMul: out[n] = input[n] @ w[inds[n]] + b[inds[n]]
// N=262144 rows, 1024 experts, in=out=32, fp32.
//
// v7 = v6 (hist -> class-major counts, 1-block scan, 4-block offsets,
// LDS-cursor scatter) + ONE change: condmul eliminates its inner-loop LDS
// traffic (v1/v6: 32 ds_read_b128 per lane-iter ~ 20us of LDS-pipe issue
// per CU) by K-SPLITTING the weight slice across lane pairs:
//   512 threads = (rg 0..31, kh 0..1, oq 0..7); lane holds w[kh*16..+15]
//   [oq*4..+3] in 16 float4 regs (64 VGPR, loaded once per block), loads
//   half an input row, 64 FMAs, one __shfl_xor(8) cross-kh reduce.
// ~110 VGPR -> 4 waves/SIMD (v3's full-w-in-reg needed 128 w-VGPRs alone
// and fell to 2 waves/SIMD = +25us latency regression).
// Fixed harness overhead: 2x ~44us 256MiB workspace-poison fills dominate
// dur_us; controllable kernel budget target ~31us.

#define N_ROWS      262144
#define N_CLASSES   1024
#define IN_F        32
#define OUT_F       32
#define HB          64
#define ROWS_PER_HB (N_ROWS / HB)   // 4096, exact

// ---------------- K1: per-block histogram (LDS atomics) ----------------
// Writes CLASS-MAJOR: bcT[c*HB + b].
__global__ __launch_bounds__(256) void k_hist(const int* __restrict__ inds,
                                              int* __restrict__ bcT) {
    __shared__ int h[N_CLASSES];
    const int tid = threadIdx.x;
    for (int c = tid; c < N_CLASSES; c += 256) h[c] = 0;
    __syncthreads();
    const int base = blockIdx.x * ROWS_PER_HB;
    for (int k = 0; k < ROWS_PER_HB; k += 256)
        atomicAdd(&h[inds[base + k + tid]], 1);
    __syncthreads();
    for (int c = tid; c < N_CLASSES; c += 256)
        bcT[c * HB + blockIdx.x] = h[c];
}

// ------- K2a: single block; per-class totals + exclusive scan -> cls_off -------
__global__ __launch_bounds__(1024) void k_scan(const int* __restrict__ bcT,
                                               int* __restrict__ cls_off) {
    __shared__ int s[N_CLASSES];
    const int c = threadIdx.x;  // 1024 threads == N_CLASSES
    const int4* p = (const int4*)(bcT + c * HB);
    int total = 0;
#pragma unroll
    for (int j = 0; j < HB / 4; ++j) {
        const int4 t = p[j];
        total += t.x + t.y + t.z + t.w;
    }
    s[c] = total;
    __syncthreads();
    // Hillis-Steele inclusive scan over classes
    for (int off = 1; off < N_CLASSES; off <<= 1) {
        int v = (c >= off) ? s[c - off] : 0;
        __syncthreads();
        s[c] += v;
        __syncthreads();
    }
    cls_off[c] = s[c] - total;  // exclusive prefix = class base
    if (c == N_CLASSES - 1) cls_off[N_CLASSES] = s[c];  // == N_ROWS
}

// ------- K2b: per-class prefix over hist-blocks (4 blocks x 256 threads) -------
__global__ __launch_bounds__(256) void k_offsets(int* __restrict__ bcT,
                                                 const int* __restrict__ cls_off) {
    const int c = blockIdx.x * 256 + threadIdx.x;
    int run = cls_off[c];
    int4* p = (int4*)(bcT + c * HB);
#pragma unroll
    for (int j = 0; j < HB / 4; ++j) {
        const int4 t = p[j];
        int4 o;
        o.x = run; run += t.x;
        o.y = run; run += t.y;
        o.z = run; run += t.z;
        o.w = run; run += t.w;
        p[j] = o;
    }
}

// ---------------- K3: scatter row ids into buckets (LDS cursors) ----------------
__global__ __launch_bounds__(256) void k_scatter(const int* __restrict__ inds,
                                                 const int* __restrict__ bcT,
                                                 int* __restrict__ rowids) {
    __shared__ int cur[N_CLASSES];
    const int tid = threadIdx.x;
    for (int c = tid; c < N_CLASSES; c += 256)
        cur[c] = bcT[c * HB + blockIdx.x];
    __syncthreads();
    const int base = blockIdx.x * ROWS_PER_HB;
    for (int k = 0; k < ROWS_PER_HB; k += 256) {
        const int row = base + k + tid;
        const int c = inds[row];
        const int pos = atomicAdd(&cur[c], 1);
        rowids[pos] = row;
    }
}

// -------- K4: one block per expert; K-split w in regs, shuffle reduce --------
// 512 threads = 8 waves. tid -> oq = tid&7 (output quad), kh = (tid>>3)&1
// (K half), rg = tid>>4 (row slot 0..31). Lane keeps w[kh*16+j][oq*4..+3]
// (j=0..15) in 16 float4 regs; per iter loads half an input row (4 float4),
// 64 scalar FMAs, then cross-kh __shfl_xor(8) reduce; kh=0 adds bias+stores.
// No LDS at all; ~110 VGPR -> 4 waves/SIMD.
__global__ __launch_bounds__(512, 4) void k_condmul(const float* __restrict__ input,
                                                    const float* __restrict__ w,
                                                    const float* __restrict__ bias,
                                                    const int* __restrict__ rowids,
                                                    const int* __restrict__ cls_off,
                                                    float* __restrict__ out) {
    const int cls = blockIdx.x;
    const int tid = threadIdx.x;
    const int oq = tid & 7;
    const int kh = (tid >> 3) & 1;
    const int rg = tid >> 4;   // 0..31

    const int start = cls_off[cls];
    const int count = cls_off[cls + 1] - start;
    if (count <= 0) return;

    // per-lane w slice: rows kh*16..kh*16+15, cols oq*4..oq*4+3.
    // Wave pattern per load: 16 distinct 16B addrs (broadcast across rg).
    const float4* w4 = (const float4*)(w + (size_t)cls * (IN_F * OUT_F)) + (size_t)kh * 16 * (OUT_F / 4) + oq;
    float4 wk[16];
#pragma unroll
    for (int j = 0; j < 16; ++j) wk[j] = w4[(size_t)j * (OUT_F / 4)];

    const float4 bv = ((const float4*)(bias + (size_t)cls * OUT_F))[oq];

    const int iters = (count + 31) >> 5;
    for (int it = 0; it < iters; ++it) {
        const int ri = it * 32 + rg;
        const bool valid = ri < count;
        const int idx = valid ? ri : (count - 1);
        const int row = rowids[start + idx];

        const float4* xin = (const float4*)(input + (size_t)row * IN_F + kh * 16);
        float4 x[4];
#pragma unroll
        for (int j = 0; j < 4; ++j) x[j] = xin[j];

        float4 acc = {0.f, 0.f, 0.f, 0.f};
#pragma unroll
        for (int j = 0; j < 4; ++j) {
            const float a0 = x[j].x, a1 = x[j].y, a2 = x[j].z, a3 = x[j].w;
            const float4 w0 = wk[4 * j + 0];
            const float4 w1 = wk[4 * j + 1];
            const float4 w2 = wk[4 * j + 2];
            const float4 w3 = wk[4 * j + 3];
            acc.x += a0 * w0.x; acc.y += a0 * w0.y; acc.z += a0 * w0.z; acc.w += a0 * w0.w;
            acc.x += a1 * w1.x; acc.y += a1 * w1.y; acc.z += a1 * w1.z; acc.w += a1 * w1.w;
            acc.x += a2 * w2.x; acc.y += a2 * w2.y; acc.z += a2 * w2.z; acc.w += a2 * w2.w;
            acc.x += a3 * w3.x; acc.y += a3 * w3.y; acc.z += a3 * w3.z; acc.w += a3 * w3.w;
        }
        // cross-kh reduce: partner lane is tid^8 (same wave)
        acc.x += __shfl_xor(acc.x, 8);
        acc.y += __shfl_xor(acc.y, 8);
        acc.z += __shfl_xor(acc.z, 8);
        acc.w += __shfl_xor(acc.w, 8);

        if (valid && kh == 0) {
            float4 o;
            o.x = acc.x + bv.x;
            o.y = acc.y + bv.y;
            o.z = acc.z + bv.z;
            o.w = acc.w + bv.w;
            ((float4*)(out + (size_t)row * OUT_F))[oq] = o;
        }
    }
}

// ---------------- fallback: direct gather (used only if ws too small) ----------------
__global__ __launch_bounds__(256) void k_naive(const float* __restrict__ input,
                                               const int* __restrict__ inds,
                                               const float* __restrict__ w,
                                               const float* __restrict__ bias,
                                               float* __restrict__ out) {
    const int tid = threadIdx.x;
    const int oq = tid & 7;
    const int rg = tid >> 3;
    const int row = blockIdx.x * 32 + rg;
    if (row >= N_ROWS) return;
    const int c = inds[row];
    const float4* xin = (const float4*)(input + (size_t)row * IN_F);
    const float4* wr = (const float4*)(w + (size_t)c * IN_F * OUT_F);
    float4 acc = ((const float4*)(bias + (size_t)c * OUT_F))[oq];
#pragma unroll
    for (int j = 0; j < 8; ++j) {
        const float4 xv = xin[j];
        const float a0 = xv.x, a1 = xv.y, a2 = xv.z, a3 = xv.w;
        const float4 w0 = wr[(j * 4 + 0) * (OUT_F / 4) + oq];
        const float4 w1 = wr[(j * 4 + 1) * (OUT_F / 4) + oq];
        const float4 w2 = wr[(j * 4 + 2) * (OUT_F / 4) + oq];
        const float4 w3 = wr[(j * 4 + 3) * (OUT_F / 4) + oq];
        acc.x += a0 * w0.x; acc.y += a0 * w0.y; acc.z += a0 * w0.z; acc.w += a0 * w0.w;
        acc.x += a1 * w1.x; acc.y += a1 * w1.y; acc.z += a1 * w1.z; acc.w += a1 * w1.w;
        acc.x += a2 * w2.x; acc.y += a2 * w2.y; acc.z += a2 * w2.z; acc.w += a2 * w2.w;
        acc.x += a3 * w3.x; acc.y += a3 * w3.y; acc.z += a3 * w3.z; acc.w += a3 * w3.w;
    }
    ((float4*)(out + (size_t)row * OUT_F))[oq] = acc;
}

extern "C" void kernel_launch(void* const* d_in, const int* in_sizes, int n_in,
                              void* d_out, int out_size, void* d_ws, size_t ws_size,
                              hipStream_t stream) {
    const float* input = (const float*)d_in[0];  // [N, 32] fp32
    const int*   inds  = (const int*)d_in[1];    // [N] int32
    const float* w     = (const float*)d_in[2];  // [1024, 32, 32] fp32
    const float* bias  = (const float*)d_in[3];  // [1024, 1, 32] fp32
    float* out = (float*)d_out;                  // [N, 32] fp32

    // ws layout (ints): bcT[1024][HB] | cls_off[1025] (+3 pad) | rowids[N]
    int* ws = (int*)d_ws;
    int* bcT     = ws;                               // class-major counts/offsets
    int* cls_off = ws + N_CLASSES * HB;
    int* rowids  = cls_off + N_CLASSES + 1 + 3;
    const size_t need = (size_t)(N_CLASSES * HB + N_CLASSES + 4 + N_ROWS) * sizeof(int);

    if (ws_size >= need) {
        k_hist<<<HB, 256, 0, stream>>>(inds, bcT);
        k_scan<<<1, 1024, 0, stream>>>(bcT, cls_off);
        k_offsets<<<N_CLASSES / 256, 256, 0, stream>>>(bcT, cls_off);
        k_scatter<<<HB, 256, 0, stream>>>(inds, bcT, rowids);
        k_condmul<<<N_CLASSES, 512, 0, stream>>>(input, w, bias, rowids, cls_off, out);
    } else {
        k_naive<<<N_ROWS / 32, 256, 0, stream>>>(input, inds, w, bias, out);
    }
}